// Round 5
// baseline (191.335 us; speedup 1.0000x reference)
//
#include <hip/hip_runtime.h>

// Attention: B=256,H=16,NQ=NK=49,D=64, fp32 in/out.
// R5: each block processes TT=4 heads (grid 1024 = 4 blocks/CU resident).
// Software pipeline: head t+1's global loads issue into registers right after
// head t's LDS staging, draining during head t's compute (hides load latency
// + vmcnt(0) barrier drain). Vt swizzle reverted (plain transpose writes are
// 2-way bank = free; R4's swizzle raised conflicts 1.18M->1.97M).
// bf16 MFMA 16x16x32; no max-subtract softmax; P aliases Qs; fp32 epilogue.

#define NQA 49
#define DD  64
#define ST  72   // LDS row stride (bf16); 144 B keeps b128 frag reads aligned.
#define TT  4    // heads per block

typedef __bf16 bf16x4 __attribute__((ext_vector_type(4)));
typedef __bf16 bf16x8 __attribute__((ext_vector_type(8)));
typedef float  f32x4  __attribute__((ext_vector_type(4)));

__global__ __launch_bounds__(256, 4)
void attn49_kernel(const float* __restrict__ Q, const float* __restrict__ K,
                   const float* __restrict__ V, float* __restrict__ O) {
    __shared__ __bf16 Qs[64 * ST];   // Q*scale rows; P aliases after phase 1
    __shared__ __bf16 Ks[64 * ST];   // K rows
    __shared__ __bf16 Vt[64 * ST];   // V^T: Vt[d*ST + k]

    const int tid = threadIdx.x;
    const int f  = tid & 15;        // float4 col index in 64-wide row
    const int r0 = tid >> 4;        // 0..15
    const int w  = tid >> 6;        // wave 0..3 owns S/O rows 16w..16w+15
    const int lr = tid & 15;
    const int lg = (tid >> 4) & 3;  // quad
    const int head0 = blockIdx.x * TT;

    float4 qv[4], kv[4], vv[4];     // staged regs for the NEXT head

    // ---- prologue: issue loads for head0 ----
    {
        const size_t base = (size_t)head0 * (NQA * DD);
        #pragma unroll
        for (int it = 0; it < 4; ++it) {
            const int r = r0 + 16 * it;
            float4 z = {0.f, 0.f, 0.f, 0.f};
            qv[it] = z; kv[it] = z; vv[it] = z;
            if (r < NQA) {
                qv[it] = *(const float4*)(Q + base + r * DD + 4 * f);
                kv[it] = *(const float4*)(K + base + r * DD + 4 * f);
                vv[it] = *(const float4*)(V + base + r * DD + 4 * f);
            }
        }
    }

    #pragma unroll 1
    for (int t = 0; t < TT; ++t) {
        __syncthreads();   // previous head's LDS reads complete (t=0: no-op)

        // ---- stage regs -> LDS (bf16 cvt; V transposed, pad cols zeroed) ----
        #pragma unroll
        for (int it = 0; it < 4; ++it) {
            const int r = r0 + 16 * it;
            bf16x4 qb = { (__bf16)(0.125f * qv[it].x), (__bf16)(0.125f * qv[it].y),
                          (__bf16)(0.125f * qv[it].z), (__bf16)(0.125f * qv[it].w) };
            bf16x4 kb = { (__bf16)kv[it].x, (__bf16)kv[it].y,
                          (__bf16)kv[it].z, (__bf16)kv[it].w };
            *(bf16x4*)&Qs[r * ST + 4 * f] = qb;
            *(bf16x4*)&Ks[r * ST + 4 * f] = kb;
            // V[r][4f+j] -> Vt[4f+j][r]; unconditional so k=49..63 are zeros.
            Vt[(4*f + 0) * ST + r] = (__bf16)vv[it].x;
            Vt[(4*f + 1) * ST + r] = (__bf16)vv[it].y;
            Vt[(4*f + 2) * ST + r] = (__bf16)vv[it].z;
            Vt[(4*f + 3) * ST + r] = (__bf16)vv[it].w;
        }

        // ---- issue loads for head t+1 (drain during this head's compute) ----
        if (t + 1 < TT) {
            const size_t base = (size_t)(head0 + t + 1) * (NQA * DD);
            #pragma unroll
            for (int it = 0; it < 4; ++it) {
                const int r = r0 + 16 * it;
                float4 z = {0.f, 0.f, 0.f, 0.f};
                qv[it] = z; kv[it] = z; vv[it] = z;
                if (r < NQA) {
                    qv[it] = *(const float4*)(Q + base + r * DD + 4 * f);
                    kv[it] = *(const float4*)(K + base + r * DD + 4 * f);
                    vv[it] = *(const float4*)(V + base + r * DD + 4 * f);
                }
            }
        }

        __syncthreads();   // staged LDS visible to all waves

        // ---- phase 1: S = (Q*scale) K^T ----
        bf16x8 aq0 = *(const bf16x8*)&Qs[(16*w + lr) * ST      + 8*lg];
        bf16x8 aq1 = *(const bf16x8*)&Qs[(16*w + lr) * ST + 32 + 8*lg];
        f32x4 acc[4] = {};
        #pragma unroll
        for (int tt = 0; tt < 4; ++tt) {
            bf16x8 b0 = *(const bf16x8*)&Ks[(16*tt + lr) * ST      + 8*lg];
            bf16x8 b1 = *(const bf16x8*)&Ks[(16*tt + lr) * ST + 32 + 8*lg];
            acc[tt] = __builtin_amdgcn_mfma_f32_16x16x32_bf16(aq0, b0, acc[tt], 0, 0, 0);
            acc[tt] = __builtin_amdgcn_mfma_f32_16x16x32_bf16(aq1, b1, acc[tt], 0, 0, 0);
        }

        // ---- softmax (no max-subtract; s bounded). Lane: rows 16w+4lg+i,
        //      col 16tt+lr. K pad rows zero => mask cols 49..63 via e3. ----
        float inv_l[4];
        #pragma unroll
        for (int i = 0; i < 4; ++i) {
            const int gq = 16*w + 4*lg + i;
            float e0 = __expf(acc[0][i]);
            float e1 = __expf(acc[1][i]);
            float e2 = __expf(acc[2][i]);
            float e3 = (lr == 0) ? __expf(acc[3][i]) : 0.f;
            float sum = (e0 + e1) + (e2 + e3);
            #pragma unroll
            for (int d = 1; d < 16; d <<= 1) sum += __shfl_xor(sum, d, 64);
            inv_l[i] = 1.f / (sum + 1e-9f);
            // P rows are wave-private; alias onto Qs (own aq frags already read)
            Qs[gq * ST +  0 + lr] = (__bf16)e0;
            Qs[gq * ST + 16 + lr] = (__bf16)e1;
            Qs[gq * ST + 32 + lr] = (__bf16)e2;
            Qs[gq * ST + 48 + lr] = (__bf16)e3;
        }

        // ---- phase 2: O = P * V ----
        bf16x8 ap0 = *(const bf16x8*)&Qs[(16*w + lr) * ST      + 8*lg];
        bf16x8 ap1 = *(const bf16x8*)&Qs[(16*w + lr) * ST + 32 + 8*lg];
        f32x4 oacc[4] = {};
        #pragma unroll
        for (int tt = 0; tt < 4; ++tt) {
            bf16x8 b0 = *(const bf16x8*)&Vt[(16*tt + lr) * ST      + 8*lg];
            bf16x8 b1 = *(const bf16x8*)&Vt[(16*tt + lr) * ST + 32 + 8*lg];
            oacc[tt] = __builtin_amdgcn_mfma_f32_16x16x32_bf16(ap0, b0, oacc[tt], 0, 0, 0);
            oacc[tt] = __builtin_amdgcn_mfma_f32_16x16x32_bf16(ap1, b1, oacc[tt], 0, 0, 0);
        }

        // ---- epilogue: scale by 1/(l+eps), store fp32 ----
        float* Og = O + (size_t)(head0 + t) * (NQA * DD);
        #pragma unroll
        for (int i = 0; i < 4; ++i) {
            const int gq = 16*w + 4*lg + i;
            if (gq < NQA) {
                #pragma unroll
                for (int tt = 0; tt < 4; ++tt)
                    Og[gq * DD + 16*tt + lr] = oacc[tt][i] * inv_l[i];
            }
        }
    }
}

extern "C" void kernel_launch(void* const* d_in, const int* in_sizes, int n_in,
                              void* d_out, int out_size, void* d_ws, size_t ws_size,
                              hipStream_t stream) {
    const float* q = (const float*)d_in[0];
    const float* k = (const float*)d_in[1];
    const float* v = (const float*)d_in[2];
    float* out = (float*)d_out;
    (void)in_sizes; (void)n_in; (void)out_size; (void)d_ws; (void)ws_size;
    attn49_kernel<<<dim3(4096 / TT), dim3(256), 0, stream>>>(q, k, v, out);
}